// Round 12
// baseline (166.940 us; speedup 1.0000x reference)
//
#include <hip/hip_runtime.h>

// Problem constants
#define BATCH 32
#define NNODE 4096
#define CIN 32
#define COUT 64
#define KDEG 5
#define POOL 4
#define NNZ_E 65536
#define BC (BATCH * CIN)         // 1024 elems per node-row
#define TBF ((size_t)NNODE * BC) // elems per Chebyshev level (bf16 storage)
#define CAP 64                   // fixed bucket capacity per row (avg degree 16)

typedef short s16x8 __attribute__((ext_vector_type(8)));
typedef float f32x4 __attribute__((ext_vector_type(4)));
typedef unsigned long long u64;

// float -> bf16 bits, round-to-nearest-even
__device__ __forceinline__ unsigned short f2bf(float f) {
    union { float f; unsigned int u; } v; v.f = f;
    unsigned int u = v.u;
    u += 0x7fffu + ((u >> 16) & 1u);
    return (unsigned short)(u >> 16);
}
__device__ __forceinline__ float bf2f(unsigned short b) {
    union { float f; unsigned int u; } v; v.u = ((unsigned int)b) << 16;
    return v.f;
}
__device__ __forceinline__ u64 pack4(float a, float b, float c, float d) {
    return (u64)f2bf(a) | ((u64)f2bf(b) << 16) | ((u64)f2bf(c) << 32) | ((u64)f2bf(d) << 48);
}

// ---------------- prep2: transpose + W pack (frag-major) + edge scatter ---------
// (verified R10) Row r's edges land in es[r*64 .. r*64+cnt[r]) in arbitrary
// order. Weights packed FRAG-MAJOR (WBF, bijective): frag (k,ot), lane l=q*16+m
// holds W rows o=ot*16+m, cols c=q*8..q*8+7 at WBF[((k*4+ot)*64+l)*8+(c&7)].

__global__ void prep2_kernel(const float* __restrict__ x, unsigned short* __restrict__ t0,
                             const int* __restrict__ erow, const int* __restrict__ ecol,
                             const float* __restrict__ eval,
                             int* __restrict__ cnt, int2* __restrict__ es,
                             const float* __restrict__ W, unsigned short* __restrict__ WBF) {
    int idx = blockIdx.x * 256 + threadIdx.x;   // [0, 1048576)
    // transpose [B][N][C] fp32 -> [N][B*C] bf16, 4 elems per thread
    int n   = idx >> 8;
    int rem = idx & 255;
    int b   = rem >> 3;
    int c4  = rem & 7;
    float4 v = ((const float4*)x)[(b * NNODE + n) * 8 + c4];
    ((u64*)t0)[idx] = pack4(v.x, v.y, v.z, v.w);

    if (idx < NNZ_E) {
        int r = erow[idx];
        int pos = atomicAdd(&cnt[r], 1);
        if (pos < CAP)
            es[(r << 6) + pos] = make_int2(ecol[idx], __float_as_int(eval[idx]));
    }

    if (idx < KDEG * COUT * CIN) {
        int c = idx & 31;
        int rest = idx >> 5;
        int o = rest & 63;
        int k = rest >> 6;
        int g    = k * 4 + (o >> 4);
        int lane = ((c >> 3) << 4) + (o & 15);
        WBF[(size_t)(g * 64 + lane) * 8 + (c & 7)] =
            f2bf(W[(c * KDEG + k) * COUT + o]);
    }
}

// ---------------- two-row interleaved Chebyshev SpMM unit (round 11/12) --------
// Latency-chain attack, plain loads only (no cross-lane data movement):
//  (a) first-16-edge es loads + gathers issue UNCONDITIONALLY: es slot addrs are
//      static (beg=r<<6, CAP buffer in-bounds); poison cols clamped &(NNODE-1)
//      (pow2 -> in-bounds, gathered data always finite); poison vals masked by
//      the deg test, which resolves in parallel. 56% of rows (deg<=16) become
//      straight-line, chain = es->gather only.
//  (b) TWO rows per wave with interleaved chains -> 12 concurrent chains/SIMD.
// Accumulation order per row identical to R10 (slots ep+4j, iter b0=0,16,32,48).
// ROUND 12 FIX: grid was 2048 (NNODE/2*8/8 arithmetic slip) -> rows 2048-4095
// never computed (absmax 4.9). Correct grid = NNODE = 4096 blocks.

__device__ __forceinline__ void spmm_pair(
        const unsigned short* in, const unsigned short* sub,
        unsigned short* out, float scale, int has_sub,
        const int* cnt, const int2* es, int r0, int r1, int s, int lane) {
    int ep  = lane >> 4;               // edge-group 0..3
    int c16 = lane & 15;               // 16B col within slice
    const s16x8* in16 = (const s16x8*)in;   // row stride = 128 x 16B

    // unconditional first-16 es loads for both rows (issue immediately)
    int2 e0[4], e1[4];
#pragma unroll
    for (int j = 0; j < 4; j++) e0[j] = es[(r0 << 6) + ep + 4 * j];
#pragma unroll
    for (int j = 0; j < 4; j++) e1[j] = es[(r1 << 6) + ep + 4 * j];

    int deg0 = cnt[r0]; deg0 = deg0 > CAP ? CAP : deg0;
    int deg1 = cnt[r1]; deg1 = deg1 > CAP ? CAP : deg1;

    // unconditional gathers, poison-clamped addresses
    s16x8 xx0[4], xx1[4];
#pragma unroll
    for (int j = 0; j < 4; j++)
        xx0[j] = in16[(size_t)(e0[j].x & (NNODE - 1)) * 128 + s * 16 + c16];
#pragma unroll
    for (int j = 0; j < 4; j++)
        xx1[j] = in16[(size_t)(e1[j].x & (NNODE - 1)) * 128 + s * 16 + c16];

    float acc0[8] = {0.f,0.f,0.f,0.f,0.f,0.f,0.f,0.f};
    float acc1[8] = {0.f,0.f,0.f,0.f,0.f,0.f,0.f,0.f};

#pragma unroll
    for (int j = 0; j < 4; j++) {
        int o = ep + 4 * j;
        float v0 = o < deg0 ? __int_as_float(e0[j].y) : 0.f;
        float v1 = o < deg1 ? __int_as_float(e1[j].y) : 0.f;
#pragma unroll
        for (int t = 0; t < 8; t++) {
            acc0[t] += v0 * bf2f((unsigned short)xx0[j][t]);
            acc1[t] += v1 * bf2f((unsigned short)xx1[j][t]);
        }
    }

    // tail (deg > 16): wave-uniform trip count, both rows masked & interleaved
    int degm = deg0 > deg1 ? deg0 : deg1;
    for (int b0 = 16; b0 < degm; b0 += 16) {
#pragma unroll
        for (int j = 0; j < 4; j++) {
            int o  = b0 + ep + 4 * j;
            int i0 = o < deg0 ? o : 0;       // slot 0 in-bounds; val masked below
            int i1 = o < deg1 ? o : 0;
            int2 f0 = es[(r0 << 6) + i0];
            int2 f1 = es[(r1 << 6) + i1];
            float v0 = o < deg0 ? __int_as_float(f0.y) : 0.f;
            float v1 = o < deg1 ? __int_as_float(f1.y) : 0.f;
            s16x8 y0 = in16[(size_t)(f0.x & (NNODE - 1)) * 128 + s * 16 + c16];
            s16x8 y1 = in16[(size_t)(f1.x & (NNODE - 1)) * 128 + s * 16 + c16];
#pragma unroll
            for (int t = 0; t < 8; t++) {
                acc0[t] += v0 * bf2f((unsigned short)y0[t]);
                acc1[t] += v1 * bf2f((unsigned short)y1[t]);
            }
        }
    }

    // reduce across the 4 edge-groups (lane^16 then lane^32), both rows
#pragma unroll
    for (int t = 0; t < 8; t++) {
        acc0[t] += __shfl_xor(acc0[t], 16);
        acc0[t] += __shfl_xor(acc0[t], 32);
        acc1[t] += __shfl_xor(acc1[t], 16);
        acc1[t] += __shfl_xor(acc1[t], 32);
    }

    if (ep == 0) {
        // row r0
        {
            size_t oi = (size_t)r0 * 128 + s * 16 + c16;
            float rr[8];
            if (has_sub) {
                u64 sv0 = ((const u64*)sub)[2 * oi];
                u64 sv1 = ((const u64*)sub)[2 * oi + 1];
#pragma unroll
                for (int t = 0; t < 4; t++)
                    rr[t] = scale * acc0[t] - bf2f((unsigned short)(sv0 >> (16 * t)));
#pragma unroll
                for (int t = 0; t < 4; t++)
                    rr[4 + t] = scale * acc0[4 + t] - bf2f((unsigned short)(sv1 >> (16 * t)));
            } else {
#pragma unroll
                for (int t = 0; t < 8; t++) rr[t] = acc0[t];
            }
            union { u64 u[2]; s16x8 v; } res;
            res.u[0] = pack4(rr[0], rr[1], rr[2], rr[3]);
            res.u[1] = pack4(rr[4], rr[5], rr[6], rr[7]);
            ((s16x8*)out)[oi] = res.v;
        }
        // row r1
        {
            size_t oi = (size_t)r1 * 128 + s * 16 + c16;
            float rr[8];
            if (has_sub) {
                u64 sv0 = ((const u64*)sub)[2 * oi];
                u64 sv1 = ((const u64*)sub)[2 * oi + 1];
#pragma unroll
                for (int t = 0; t < 4; t++)
                    rr[t] = scale * acc1[t] - bf2f((unsigned short)(sv0 >> (16 * t)));
#pragma unroll
                for (int t = 0; t < 4; t++)
                    rr[4 + t] = scale * acc1[4 + t] - bf2f((unsigned short)(sv1 >> (16 * t)));
            } else {
#pragma unroll
                for (int t = 0; t < 8; t++) rr[t] = acc1[t];
            }
            union { u64 u[2]; s16x8 v; } res;
            res.u[0] = pack4(rr[0], rr[1], rr[2], rr[3]);
            res.u[1] = pack4(rr[4], rr[5], rr[6], rr[7]);
            ((s16x8*)out)[oi] = res.v;
        }
    }
}

// ---------------- standalone per-level SpMM (levels 1-4) ----------------
// grid = NNODE = 4096 blocks of 256; block = 8 rows (2/wave) x 1 slice
// (slice = bx&7 = XCD -- pinning keeps gathers L2-local; rg = bx>>3 in [0,512)).

__global__ __launch_bounds__(256, 6) void spmm_lvl_kernel(
        const unsigned short* __restrict__ in, const unsigned short* __restrict__ sub,
        unsigned short* __restrict__ out, float scale, int has_sub,
        const int* __restrict__ cnt, const int2* __restrict__ es) {
    int bx    = blockIdx.x;            // [0, 4096)
    int slice = bx & 7;
    int rg    = bx >> 3;               // [0, 512) row group of 8
    int wave  = threadIdx.x >> 6;
    int lane  = threadIdx.x & 63;
    int r0    = rg * 8 + wave;
    int r1    = r0 + 4;

    spmm_pair(in, sub, out, scale, has_sub, cnt, es, r0, r1, slice, lane);
}

// ---------------- MFMA GEMM + bias + ReLU + maxpool (verified R10) -------------
// B-frags staged once per block into LDS from frag-major WBF (coalesced), read
// conflict-free as lane x 16B. A-loads / D-layout = verified round-0 kernel.

__global__ __launch_bounds__(256) void gemm_mfma_pool_kernel(
        const unsigned short* __restrict__ tbase, const unsigned short* __restrict__ WBF,
        const float* __restrict__ bias, float* __restrict__ out) {
    __shared__ s16x8 wlds[20][64];         // 20 KB: frag (k*4+ot) x lane

    int tid  = threadIdx.x;
    int wv   = tid >> 6;
    int lane = tid & 63;

#pragma unroll
    for (int p = 0; p < 5; p++) {
        int g = wv * 5 + p;
        wlds[g][lane] = ((const s16x8*)WBF)[g * 64 + lane];
    }
    __syncthreads();

    int gtid = blockIdx.x * 256 + tid;
    int wid  = gtid >> 6;            // [0, 8192)
    int b    = wid >> 8;             // [0, 32)
    int n0   = (wid & 255) << 4;     // node tile base
    int m    = lane & 15;
    int q    = lane >> 4;

    f32x4 acc[4] = {{0.f,0.f,0.f,0.f},{0.f,0.f,0.f,0.f},
                    {0.f,0.f,0.f,0.f},{0.f,0.f,0.f,0.f}};

    const unsigned short* abase = tbase + (size_t)(n0 + m) * BC + b * CIN + q * 8;

#pragma unroll
    for (int k = 0; k < KDEG; k++) {
        s16x8 a = *(const s16x8*)(abase + (size_t)k * TBF);
#pragma unroll
        for (int ot = 0; ot < 4; ot++) {
            s16x8 bf = wlds[k * 4 + ot][lane];
            acc[ot] = __builtin_amdgcn_mfma_f32_16x16x32_bf16(a, bf, acc[ot], 0, 0, 0);
        }
    }

    size_t orow = ((size_t)b * (NNODE / POOL) + (n0 >> 2) + q) * COUT;
#pragma unroll
    for (int ot = 0; ot < 4; ot++) {
        float bi = bias[ot * 16 + m];
        float r0 = acc[ot][0] + bi; r0 = r0 > 0.f ? r0 : 0.f;
        float r1 = acc[ot][1] + bi; r1 = r1 > 0.f ? r1 : 0.f;
        float r2 = acc[ot][2] + bi; r2 = r2 > 0.f ? r2 : 0.f;
        float r3 = acc[ot][3] + bi; r3 = r3 > 0.f ? r3 : 0.f;
        float mx = r0 > r1 ? r0 : r1;
        mx = mx > r2 ? mx : r2;
        mx = mx > r3 ? mx : r3;
        out[orow + ot * 16 + m] = mx;
    }
}

// ---------------- launch: 7 dispatches ----------------

extern "C" void kernel_launch(void* const* d_in, const int* in_sizes, int n_in,
                              void* d_out, int out_size, void* d_ws, size_t ws_size,
                              hipStream_t stream) {
    const float* x    = (const float*)d_in[0];
    const float* eval = (const float*)d_in[1];
    const float* W    = (const float*)d_in[2];
    const float* bias = (const float*)d_in[3];
    const int*   erow = (const int*)d_in[4];
    const int*   ecol = (const int*)d_in[5];
    float* out = (float*)d_out;

    char* base = (char*)d_ws;
    unsigned short* tb = (unsigned short*)base;     // 5 levels x 8 MB (bf16)
    unsigned short* t0 = tb;
    unsigned short* t1 = tb + 1 * TBF;
    unsigned short* t2 = tb + 2 * TBF;
    unsigned short* t3 = tb + 3 * TBF;
    unsigned short* t4 = tb + 4 * TBF;

    size_t off = 5 * TBF * sizeof(unsigned short);
    int2* es = (int2*)(base + off);  off += (size_t)NNODE * CAP * sizeof(int2);
    int* cnt = (int*)(base + off);   off += (size_t)NNODE * sizeof(int);
    off += 32 * sizeof(int);                        // legacy bar slot, unused
    off = (off + 63) & ~(size_t)63;
    unsigned short* WBF = (unsigned short*)(base + off);

    // zero scatter cursors (d_ws re-poisoned every call -> rebuild each call)
    hipMemsetAsync(cnt, 0, NNODE * sizeof(int), stream);

    // transpose + frag-major W pack + bucket scatter
    prep2_kernel<<<TBF / 4 / 256, 256, 0, stream>>>(x, t0, erow, ecol, eval,
                                                    cnt, es, W, WBF);

    // Chebyshev levels 1-4: 2 rows/wave, unconditional first-16 prefetch
    // grid = NNODE = 4096 blocks (R11 bug: 2048 left half the rows unwritten)
    spmm_lvl_kernel<<<NNODE, 256, 0, stream>>>(t0, nullptr, t1, 1.0f, 0, cnt, es);
    spmm_lvl_kernel<<<NNODE, 256, 0, stream>>>(t1, t0, t2, 2.0f, 1, cnt, es);
    spmm_lvl_kernel<<<NNODE, 256, 0, stream>>>(t2, t1, t3, 2.0f, 1, cnt, es);
    spmm_lvl_kernel<<<NNODE, 256, 0, stream>>>(t3, t2, t4, 2.0f, 1, cnt, es);

    // MFMA GEMM + bias + relu + maxpool (B-frags via LDS)
    gemm_mfma_pool_kernel<<<(BATCH * (NNODE / 16) * 64) / 256, 256, 0, stream>>>(
        tb, WBF, bias, out);
}

// Round 13
// 154.635 us; speedup vs baseline: 1.0796x; 1.0796x over previous
//
#include <hip/hip_runtime.h>

// Problem constants
#define BATCH 32
#define NNODE 4096
#define CIN 32
#define COUT 64
#define KDEG 5
#define POOL 4
#define NNZ_E 65536
#define BC (BATCH * CIN)         // 1024 elems per node-row
#define TBF ((size_t)NNODE * BC) // elems per Chebyshev level (bf16 storage)
#define CAP 64                   // fixed bucket capacity per row (avg degree 16)

typedef short s16x8 __attribute__((ext_vector_type(8)));
typedef float f32x4 __attribute__((ext_vector_type(4)));
typedef unsigned long long u64;

// float -> bf16 bits, round-to-nearest-even
__device__ __forceinline__ unsigned short f2bf(float f) {
    union { float f; unsigned int u; } v; v.f = f;
    unsigned int u = v.u;
    u += 0x7fffu + ((u >> 16) & 1u);
    return (unsigned short)(u >> 16);
}
__device__ __forceinline__ float bf2f(unsigned short b) {
    union { float f; unsigned int u; } v; v.u = ((unsigned int)b) << 16;
    return v.f;
}
__device__ __forceinline__ u64 pack4(float a, float b, float c, float d) {
    return (u64)f2bf(a) | ((u64)f2bf(b) << 16) | ((u64)f2bf(c) << 32) | ((u64)f2bf(d) << 48);
}

// ---------------- prep2: transpose + W pack (frag-major) + edge scatter ---------
// (verified R10) Row r's edges land in es[r*64 .. r*64+cnt[r]) in arbitrary
// order. Weights packed FRAG-MAJOR (WBF, bijective): frag (k,ot), lane l=q*16+m
// holds W rows o=ot*16+m, cols c=q*8..q*8+7 at WBF[((k*4+ot)*64+l)*8+(c&7)].

__global__ void prep2_kernel(const float* __restrict__ x, unsigned short* __restrict__ t0,
                             const int* __restrict__ erow, const int* __restrict__ ecol,
                             const float* __restrict__ eval,
                             int* __restrict__ cnt, int2* __restrict__ es,
                             const float* __restrict__ W, unsigned short* __restrict__ WBF) {
    int idx = blockIdx.x * 256 + threadIdx.x;   // [0, 1048576)
    // transpose [B][N][C] fp32 -> [N][B*C] bf16, 4 elems per thread
    int n   = idx >> 8;
    int rem = idx & 255;
    int b   = rem >> 3;
    int c4  = rem & 7;
    float4 v = ((const float4*)x)[(b * NNODE + n) * 8 + c4];
    ((u64*)t0)[idx] = pack4(v.x, v.y, v.z, v.w);

    if (idx < NNZ_E) {
        int r = erow[idx];
        int pos = atomicAdd(&cnt[r], 1);
        if (pos < CAP)
            es[(r << 6) + pos] = make_int2(ecol[idx], __float_as_int(eval[idx]));
    }

    if (idx < KDEG * COUT * CIN) {
        int c = idx & 31;
        int rest = idx >> 5;
        int o = rest & 63;
        int k = rest >> 6;
        int g    = k * 4 + (o >> 4);
        int lane = ((c >> 3) << 4) + (o & 15);
        WBF[(size_t)(g * 64 + lane) * 8 + (c & 7)] =
            f2bf(W[(c * KDEG + k) * COUT + o]);
    }
}

// ---------------- one (row, slice) unit of Chebyshev SpMM -- 4-ep layout --------
// R10 verified body + two zero-cost load reorderings (round 13):
//  (a) PEELED FIRST ITERATION with pre-issued es loads: the first 4 es slot
//      addrs are static ((r<<6)+ep+4j, always in-bounds in the CAP bucket) ->
//      issued BEFORE the cnt load; vals masked by o<deg (masked lanes add
//      +0.0f, same FP order as R10 -> bit-identical); cols clamped &(NNODE-1)
//      (pow2, gathered data always finite). Startup chain cnt->es->gather
//      becomes max(cnt,es)->gather: one L2 latency removed per row.
//  (b) ISSUE-EARLY sub loads: static address, issued at entry (exec-masked
//      ep==0), consumed in the epilogue -- removes the L2/HBM latency that R10
//      serialized after the shfl reduce.
// Geometry/occupancy/traffic identical to R10 (1 row/wave, 8 waves/SIMD) --
// the clean test of the latency-chain theory (R11/12's version was confounded
// by occupancy loss + wasted gathers).

__device__ __forceinline__ s16x8 spmm_row4(
        const unsigned short* in, const unsigned short* sub,
        float scale, int has_sub, const int* cnt, const int2* es,
        int r, int s, int lane) {
    int ep  = lane >> 4;               // edge-group 0..3
    int c16 = lane & 15;               // 16B col within slice (16 x 16B = 256B)
    const s16x8* in16 = (const s16x8*)in;   // row stride = 128 x 16B

    // (a) issue-early: first-16 es loads, static in-bounds addresses
    int2 e0[4];
#pragma unroll
    for (int j = 0; j < 4; j++) e0[j] = es[(r << 6) + ep + 4 * j];

    // (b) issue-early: sub operand (consumed only in the epilogue)
    size_t oi = (size_t)r * 128 + s * 16 + c16;   // 16B units
    u64 sv0 = 0, sv1 = 0;
    if (has_sub && ep == 0) {
        sv0 = ((const u64*)sub)[2 * oi];
        sv1 = ((const u64*)sub)[2 * oi + 1];
    }

    int deg = cnt[r]; deg = deg > CAP ? CAP : deg;
    int beg = r << 6, end = beg + deg;

    float acc[8] = {0.f,0.f,0.f,0.f,0.f,0.f,0.f,0.f};

    // peeled iteration 0: slots ep+4j (j=0..3), same accumulation order as R10
    {
        s16x8 xx[4];
#pragma unroll
        for (int j = 0; j < 4; j++)
            xx[j] = in16[(size_t)(e0[j].x & (NNODE - 1)) * 128 + s * 16 + c16];
#pragma unroll
        for (int j = 0; j < 4; j++) {
            float vv = (ep + 4 * j) < deg ? __int_as_float(e0[j].y) : 0.f;
#pragma unroll
            for (int t = 0; t < 8; t++)
                acc[t] += vv * bf2f((unsigned short)xx[j][t]);
        }
    }

    // tail iterations (deg > 16): exact R10 structure, base starts at +16
    for (int base = beg + ep + 16; base < end; base += 16) {
        float vv[4];
        s16x8 xx[4];
#pragma unroll
        for (int j = 0; j < 4; j++) {
            int idx = base + 4 * j;
            int src = idx < end ? idx : beg;   // beg valid: loop was entered
            int2 e = es[src];
            vv[j] = idx < end ? __int_as_float(e.y) : 0.f;
            xx[j] = in16[(size_t)e.x * 128 + s * 16 + c16];
        }
#pragma unroll
        for (int j = 0; j < 4; j++)
#pragma unroll
            for (int t = 0; t < 8; t++)
                acc[t] += vv[j] * bf2f((unsigned short)xx[j][t]);
    }

    // reduce across the 4 edge-groups (lane^16 then lane^32)
#pragma unroll
    for (int t = 0; t < 8; t++) {
        acc[t] += __shfl_xor(acc[t], 16);
        acc[t] += __shfl_xor(acc[t], 32);
    }

    union { u64 u[2]; s16x8 v; } res;
    res.u[0] = 0; res.u[1] = 0;
    if (ep == 0) {
        float rr[8];
        if (has_sub) {
#pragma unroll
            for (int t = 0; t < 4; t++)
                rr[t] = scale * acc[t] - bf2f((unsigned short)(sv0 >> (16 * t)));
#pragma unroll
            for (int t = 0; t < 4; t++)
                rr[4 + t] = scale * acc[4 + t] - bf2f((unsigned short)(sv1 >> (16 * t)));
        } else {
#pragma unroll
            for (int t = 0; t < 8; t++) rr[t] = acc[t];
        }
        res.u[0] = pack4(rr[0], rr[1], rr[2], rr[3]);
        res.u[1] = pack4(rr[4], rr[5], rr[6], rr[7]);
    }
    return res.v;
}

// ---------------- standalone per-level SpMM (levels 1-4) ----------------
// grid = NNODE*2 = 8192 blocks of 256; block = 4 rows x 1 slice
// (slice = bx&7 = XCD -- the pinning that makes gathers L2-local).

__global__ __launch_bounds__(256, 8) void spmm_lvl_kernel(
        const unsigned short* __restrict__ in, const unsigned short* __restrict__ sub,
        unsigned short* __restrict__ out, float scale, int has_sub,
        const int* __restrict__ cnt, const int2* __restrict__ es) {
    int bx    = blockIdx.x;
    int slice = bx & 7;
    int rg    = bx >> 3;
    int wave  = threadIdx.x >> 6;
    int lane  = threadIdx.x & 63;
    int r     = rg * 4 + wave;

    s16x8 res = spmm_row4(in, sub, scale, has_sub, cnt, es, r, slice, lane);
    if (lane < 16)
        ((s16x8*)out)[(size_t)r * 128 + slice * 16 + lane] = res;  // keep slice in L2
}

// ---------------- MFMA GEMM + bias + ReLU + maxpool (verified R10) -------------
// B-frags staged once per block into LDS from frag-major WBF (coalesced), read
// conflict-free as lane x 16B. A-loads / D-layout = verified round-0 kernel.

__global__ __launch_bounds__(256) void gemm_mfma_pool_kernel(
        const unsigned short* __restrict__ tbase, const unsigned short* __restrict__ WBF,
        const float* __restrict__ bias, float* __restrict__ out) {
    __shared__ s16x8 wlds[20][64];         // 20 KB: frag (k*4+ot) x lane

    int tid  = threadIdx.x;
    int wv   = tid >> 6;
    int lane = tid & 63;

#pragma unroll
    for (int p = 0; p < 5; p++) {
        int g = wv * 5 + p;
        wlds[g][lane] = ((const s16x8*)WBF)[g * 64 + lane];
    }
    __syncthreads();

    int gtid = blockIdx.x * 256 + tid;
    int wid  = gtid >> 6;            // [0, 8192)
    int b    = wid >> 8;             // [0, 32)
    int n0   = (wid & 255) << 4;     // node tile base
    int m    = lane & 15;
    int q    = lane >> 4;

    f32x4 acc[4] = {{0.f,0.f,0.f,0.f},{0.f,0.f,0.f,0.f},
                    {0.f,0.f,0.f,0.f},{0.f,0.f,0.f,0.f}};

    const unsigned short* abase = tbase + (size_t)(n0 + m) * BC + b * CIN + q * 8;

#pragma unroll
    for (int k = 0; k < KDEG; k++) {
        s16x8 a = *(const s16x8*)(abase + (size_t)k * TBF);
#pragma unroll
        for (int ot = 0; ot < 4; ot++) {
            s16x8 bf = wlds[k * 4 + ot][lane];
            acc[ot] = __builtin_amdgcn_mfma_f32_16x16x32_bf16(a, bf, acc[ot], 0, 0, 0);
        }
    }

    size_t orow = ((size_t)b * (NNODE / POOL) + (n0 >> 2) + q) * COUT;
#pragma unroll
    for (int ot = 0; ot < 4; ot++) {
        float bi = bias[ot * 16 + m];
        float r0 = acc[ot][0] + bi; r0 = r0 > 0.f ? r0 : 0.f;
        float r1 = acc[ot][1] + bi; r1 = r1 > 0.f ? r1 : 0.f;
        float r2 = acc[ot][2] + bi; r2 = r2 > 0.f ? r2 : 0.f;
        float r3 = acc[ot][3] + bi; r3 = r3 > 0.f ? r3 : 0.f;
        float mx = r0 > r1 ? r0 : r1;
        mx = mx > r2 ? mx : r2;
        mx = mx > r3 ? mx : r3;
        out[orow + ot * 16 + m] = mx;
    }
}

// ---------------- launch: 7 dispatches ----------------

extern "C" void kernel_launch(void* const* d_in, const int* in_sizes, int n_in,
                              void* d_out, int out_size, void* d_ws, size_t ws_size,
                              hipStream_t stream) {
    const float* x    = (const float*)d_in[0];
    const float* eval = (const float*)d_in[1];
    const float* W    = (const float*)d_in[2];
    const float* bias = (const float*)d_in[3];
    const int*   erow = (const int*)d_in[4];
    const int*   ecol = (const int*)d_in[5];
    float* out = (float*)d_out;

    char* base = (char*)d_ws;
    unsigned short* tb = (unsigned short*)base;     // 5 levels x 8 MB (bf16)
    unsigned short* t0 = tb;
    unsigned short* t1 = tb + 1 * TBF;
    unsigned short* t2 = tb + 2 * TBF;
    unsigned short* t3 = tb + 3 * TBF;
    unsigned short* t4 = tb + 4 * TBF;

    size_t off = 5 * TBF * sizeof(unsigned short);
    int2* es = (int2*)(base + off);  off += (size_t)NNODE * CAP * sizeof(int2);
    int* cnt = (int*)(base + off);   off += (size_t)NNODE * sizeof(int);
    off += 32 * sizeof(int);                        // legacy bar slot, unused
    off = (off + 63) & ~(size_t)63;
    unsigned short* WBF = (unsigned short*)(base + off);

    // zero scatter cursors (d_ws re-poisoned every call -> rebuild each call)
    hipMemsetAsync(cnt, 0, NNODE * sizeof(int), stream);

    // transpose + frag-major W pack + bucket scatter
    prep2_kernel<<<TBF / 4 / 256, 256, 0, stream>>>(x, t0, erow, ecol, eval,
                                                    cnt, es, W, WBF);

    // Chebyshev levels 1-4 (R10 geometry: 8192 blocks, 1 row/wave)
    spmm_lvl_kernel<<<NNODE * 2, 256, 0, stream>>>(t0, nullptr, t1, 1.0f, 0, cnt, es);
    spmm_lvl_kernel<<<NNODE * 2, 256, 0, stream>>>(t1, t0, t2, 2.0f, 1, cnt, es);
    spmm_lvl_kernel<<<NNODE * 2, 256, 0, stream>>>(t2, t1, t3, 2.0f, 1, cnt, es);
    spmm_lvl_kernel<<<NNODE * 2, 256, 0, stream>>>(t3, t2, t4, 2.0f, 1, cnt, es);

    // MFMA GEMM + bias + relu + maxpool (B-frags via LDS)
    gemm_mfma_pool_kernel<<<(BATCH * (NNODE / 16) * 64) / 256, 256, 0, stream>>>(
        tb, WBF, bias, out);
}